// Round 1
// baseline (554.529 us; speedup 1.0000x reference)
//
#include <hip/hip_runtime.h>
#include <hip/hip_bf16.h>

// ---------------------------------------------------------------------------
// MultiheadAttention fused pipeline for MI355X (gfx950)
// B=2, S=S'=2048, H=16, D_MODEL=1024, dk=dv=64
// outputs: out [2,2048,1024] fp32, attn [2,16,2048,2048] fp32 (concat in d_out)
// ---------------------------------------------------------------------------

typedef __bf16 bf16x8 __attribute__((ext_vector_type(8)));
typedef __bf16 bf16x4 __attribute__((ext_vector_type(4)));
typedef float  f32x4  __attribute__((ext_vector_type(4)));

#define NUM_HEAD 16
#define SEQ 2048
#define DMODEL 1024
#define DK 64
#define MROWS 4096      // B*S
#define SP 2052         // padded score row stride (floats): 2052%32=4 -> conflict-free-ish

// ---------------------------------------------------------------------------
// LayerNorm(query) -> bf16, one block (256 thr) per row of 1024
// ---------------------------------------------------------------------------
__global__ __launch_bounds__(256) void ln_kernel(const float* __restrict__ x,
                                                 const float* __restrict__ g,
                                                 const float* __restrict__ bt,
                                                 __bf16* __restrict__ y) {
    int row = blockIdx.x, tid = threadIdx.x;
    __shared__ float red[2][4];
    float4 v = ((const float4*)(x + (size_t)row * DMODEL))[tid];
    float s  = v.x + v.y + v.z + v.w;
    float sq = v.x * v.x + v.y * v.y + v.z * v.z + v.w * v.w;
    #pragma unroll
    for (int o = 32; o; o >>= 1) { s += __shfl_xor(s, o, 64); sq += __shfl_xor(sq, o, 64); }
    int wv = tid >> 6;
    if ((tid & 63) == 0) { red[0][wv] = s; red[1][wv] = sq; }
    __syncthreads();
    s  = red[0][0] + red[0][1] + red[0][2] + red[0][3];
    sq = red[1][0] + red[1][1] + red[1][2] + red[1][3];
    float mu  = s * (1.0f / DMODEL);
    float var = sq * (1.0f / DMODEL) - mu * mu;
    float rs  = rsqrtf(var + 1e-6f);
    float4 gg = ((const float4*)g)[tid];
    float4 bb = ((const float4*)bt)[tid];
    bf16x4 o;
    o[0] = (__bf16)((v.x - mu) * rs * gg.x + bb.x);
    o[1] = (__bf16)((v.y - mu) * rs * gg.y + bb.y);
    o[2] = (__bf16)((v.z - mu) * rs * gg.z + bb.z);
    o[3] = (__bf16)((v.w - mu) * rs * gg.w + bb.w);
    *(bf16x4*)&y[(size_t)row * DMODEL + tid * 4] = o;
}

// ---------------------------------------------------------------------------
// fp32 -> bf16 cast, 4 elems/thread, exact grids
// ---------------------------------------------------------------------------
__global__ __launch_bounds__(256) void cast_kernel(const float* __restrict__ x,
                                                   __bf16* __restrict__ y) {
    int i = blockIdx.x * 256 + threadIdx.x;
    float4 v = ((const float4*)x)[i];
    bf16x4 o = {(__bf16)v.x, (__bf16)v.y, (__bf16)v.z, (__bf16)v.w};
    *(bf16x4*)&y[(size_t)i * 4] = o;
}

// ---------------------------------------------------------------------------
// GEMM C[M,N] = A[M,1024] * W^T  (W row-major [N,1024])
// 128x128 tile, 4 waves (2x2), each wave 64x64 = 4x4 frags of 16x16x32 MFMA.
// MODE 0: Q-proj  -> bf16 [b,h,s,64], scale 1/8 folded
// MODE 1: K-proj  -> bf16 [b,h,s,64]
// MODE 2: V-proj  -> bf16 [b,h,64,s']  (transposed for PV fragment loads)
// MODE 3: out-proj-> fp32 d_out + residual
// ---------------------------------------------------------------------------
template <int MODE>
__global__ __launch_bounds__(256) void gemm_bt(const __bf16* __restrict__ A,
                                               const __bf16* __restrict__ Bw,
                                               void* __restrict__ Cout,
                                               const float* __restrict__ residual,
                                               int M, int N) {
    const int Kd = 1024;
    __shared__ __bf16 As[128][32];
    __shared__ __bf16 Bs[128][32];
    int tiles_n = N >> 7;
    int tm = blockIdx.x / tiles_n, tn = blockIdx.x % tiles_n;
    int tid = threadIdx.x, lane = tid & 63, wv = tid >> 6;
    int wr = (wv >> 1) * 64, wc = (wv & 1) * 64;
    int lr = lane & 15, lg = lane >> 4;
    int r0 = tid >> 2, kk0 = (tid & 3) * 8;   // staging chunk: rows r0 and r0+64

    f32x4 acc[4][4] = {};
    const __bf16* Arow = A  + (size_t)(tm * 128) * Kd;
    const __bf16* Brow = Bw + (size_t)(tn * 128) * Kd;

    for (int kt = 0; kt < Kd; kt += 32) {
        int4 av0 = *(const int4*)&Arow[(size_t)r0 * Kd + kt + kk0];
        int4 av1 = *(const int4*)&Arow[(size_t)(r0 + 64) * Kd + kt + kk0];
        int4 bv0 = *(const int4*)&Brow[(size_t)r0 * Kd + kt + kk0];
        int4 bv1 = *(const int4*)&Brow[(size_t)(r0 + 64) * Kd + kt + kk0];
        __syncthreads();  // previous iter's LDS reads done
        *(int4*)&As[r0][kk0]      = av0;
        *(int4*)&As[r0 + 64][kk0] = av1;
        *(int4*)&Bs[r0][kk0]      = bv0;
        *(int4*)&Bs[r0 + 64][kk0] = bv1;
        __syncthreads();
        bf16x8 af[4], bg[4];
        #pragma unroll
        for (int m = 0; m < 4; ++m) af[m] = *(bf16x8*)&As[wr + m * 16 + lr][lg * 8];
        #pragma unroll
        for (int n = 0; n < 4; ++n) bg[n] = *(bf16x8*)&Bs[wc + n * 16 + lr][lg * 8];
        #pragma unroll
        for (int m = 0; m < 4; ++m)
            #pragma unroll
            for (int n = 0; n < 4; ++n)
                acc[m][n] = __builtin_amdgcn_mfma_f32_16x16x32_bf16(af[m], bg[n], acc[m][n], 0, 0, 0);
    }

    #pragma unroll
    for (int m = 0; m < 4; ++m) {
        #pragma unroll
        for (int n = 0; n < 4; ++n) {
            #pragma unroll
            for (int r = 0; r < 4; ++r) {
                int grow = tm * 128 + wr + m * 16 + lg * 4 + r;
                int gcol = tn * 128 + wc + n * 16 + lr;
                float val = acc[m][n][r];
                if (MODE == 0) val *= 0.125f;  // 1/sqrt(dk)
                if (MODE == 0 || MODE == 1) {
                    int b = grow >> 11, ss = grow & 2047, h = gcol >> 6, d = gcol & 63;
                    ((__bf16*)Cout)[((size_t)(b * NUM_HEAD + h) * SEQ + ss) * DK + d] = (__bf16)val;
                } else if (MODE == 2) {
                    int b = grow >> 11, ss = grow & 2047, h = gcol >> 6, d = gcol & 63;
                    ((__bf16*)Cout)[((size_t)(b * NUM_HEAD + h) * DK + d) * SEQ + ss] = (__bf16)val;
                } else {
                    size_t idx = (size_t)grow * DMODEL + gcol;
                    ((float*)Cout)[idx] = val + residual[idx];
                }
            }
        }
    }
}

// ---------------------------------------------------------------------------
// Attention: one block per (b,h, 16-query-row tile). 4 waves.
// Full 16x2048 score tile in LDS (fp32, padded). Exact softmax, probabilities
// written to d_out attn region and reused from LDS for PV.
// ---------------------------------------------------------------------------
__global__ __launch_bounds__(256) void attn_kernel(const __bf16* __restrict__ Qp,
                                                   const __bf16* __restrict__ Kp,
                                                   const __bf16* __restrict__ Vt,
                                                   float* __restrict__ attn_out,
                                                   __bf16* __restrict__ out_heads) {
    __shared__ float  sc[16][SP];       // 131,328 B
    __shared__ __bf16 qt[16][DK];       // 2 KB

    int bid = blockIdx.x;
    int bh = bid >> 7;          // b*16+h
    int qtile = bid & 127;
    int qbase = qtile * 16;
    int tid = threadIdx.x, lane = tid & 63, wv = tid >> 6;
    int lr = lane & 15, lg = lane >> 4;

    const __bf16* Qh = Qp + (size_t)bh * SEQ * DK;
    const __bf16* Kh = Kp + (size_t)bh * SEQ * DK;
    const __bf16* Vh = Vt + (size_t)bh * DK * SEQ;

    {   // load Q tile (1024 elems, 4 per thread)
        int idx = tid * 4;
        int r = idx >> 6, d0 = idx & 63;
        *(bf16x4*)&qt[r][d0] = *(const bf16x4*)&Qh[(size_t)(qbase + r) * DK + d0];
    }
    __syncthreads();

    bf16x8 a0 = *(bf16x8*)&qt[lr][lg * 8];
    bf16x8 a1 = *(bf16x8*)&qt[lr][32 + lg * 8];

    // --- QK^T: wave wv covers key-col tiles [wv*512, wv*512+512) ---
    #pragma unroll 4
    for (int t = 0; t < 32; ++t) {
        int c0 = (wv * 32 + t) * 16;
        bf16x8 b0 = *(const bf16x8*)&Kh[(size_t)(c0 + lr) * DK + lg * 8];
        bf16x8 b1 = *(const bf16x8*)&Kh[(size_t)(c0 + lr) * DK + 32 + lg * 8];
        f32x4 acc = {0.f, 0.f, 0.f, 0.f};
        acc = __builtin_amdgcn_mfma_f32_16x16x32_bf16(a0, b0, acc, 0, 0, 0);
        acc = __builtin_amdgcn_mfma_f32_16x16x32_bf16(a1, b1, acc, 0, 0, 0);
        #pragma unroll
        for (int r = 0; r < 4; ++r) sc[lg * 4 + r][c0 + lr] = acc[r];
    }
    __syncthreads();

    // --- softmax: wave wv owns rows wv*4 .. wv*4+3, whole wave per row ---
    float* attn_base = attn_out + ((size_t)bh * SEQ + qbase) * SEQ;
    for (int rr = wv * 4; rr < wv * 4 + 4; ++rr) {
        float ev[32];
        float mx = -1e30f;
        #pragma unroll
        for (int j = 0; j < 32; ++j) { ev[j] = sc[rr][lane + 64 * j]; mx = fmaxf(mx, ev[j]); }
        #pragma unroll
        for (int o = 32; o; o >>= 1) mx = fmaxf(mx, __shfl_xor(mx, o, 64));
        float s = 0.f;
        #pragma unroll
        for (int j = 0; j < 32; ++j) { ev[j] = __expf(ev[j] - mx); s += ev[j]; }
        #pragma unroll
        for (int o = 32; o; o >>= 1) s += __shfl_xor(s, o, 64);
        float inv = 1.0f / s;
        #pragma unroll
        for (int j = 0; j < 32; ++j) {
            float p = ev[j] * inv;
            sc[rr][lane + 64 * j] = p;
            attn_base[(size_t)rr * SEQ + lane + 64 * j] = p;
        }
    }
    __syncthreads();

    // --- PV: out[16 x 64] = P[16 x 2048] * V[2048 x 64]; wave wv -> d-cols wv*16.. ---
    f32x4 acc = {0.f, 0.f, 0.f, 0.f};
    #pragma unroll 4
    for (int kb = 0; kb < 64; ++kb) {
        bf16x8 pa;
        const float* prow = &sc[lr][kb * 32 + lg * 8];
        #pragma unroll
        for (int j = 0; j < 8; ++j) pa[j] = (__bf16)prow[j];
        bf16x8 vb = *(const bf16x8*)&Vh[(size_t)(wv * 16 + lr) * SEQ + kb * 32 + lg * 8];
        acc = __builtin_amdgcn_mfma_f32_16x16x32_bf16(pa, vb, acc, 0, 0, 0);
    }
    int b = bh >> 4, h = bh & 15;
    #pragma unroll
    for (int r = 0; r < 4; ++r) {
        int row = lg * 4 + r;
        out_heads[((size_t)(b * SEQ + qbase + row)) * DMODEL + h * DK + wv * 16 + lr] = (__bf16)acc[r];
    }
}

// ---------------------------------------------------------------------------
extern "C" void kernel_launch(void* const* d_in, const int* in_sizes, int n_in,
                              void* d_out, int out_size, void* d_ws, size_t ws_size,
                              hipStream_t stream) {
    const float* query = (const float*)d_in[0];
    const float* key   = (const float*)d_in[1];
    const float* value = (const float*)d_in[2];
    const float* w_q   = (const float*)d_in[3];
    const float* w_k   = (const float*)d_in[4];
    const float* w_v   = (const float*)d_in[5];
    const float* w_o   = (const float*)d_in[6];
    const float* lng   = (const float*)d_in[7];
    const float* lnb   = (const float*)d_in[8];

    char* ws = (char*)d_ws;
    __bf16* qn  = (__bf16*)(ws);                    // 8 MB  LN(query) bf16
    __bf16* kb  = (__bf16*)(ws + ( 8u << 20));      // 8 MB  key bf16
    __bf16* vb  = (__bf16*)(ws + (16u << 20));      // 8 MB  value bf16
    __bf16* wqb = (__bf16*)(ws + (24u << 20));      // 2 MB
    __bf16* wkb = (__bf16*)(ws + (26u << 20));      // 2 MB
    __bf16* wvb = (__bf16*)(ws + (28u << 20));      // 2 MB
    __bf16* wob = (__bf16*)(ws + (30u << 20));      // 2 MB
    __bf16* Qp  = (__bf16*)(ws + (32u << 20));      // 8 MB  [b,h,s,64] (x1/8)
    __bf16* Kp  = (__bf16*)(ws + (40u << 20));      // 8 MB  [b,h,s,64]
    __bf16* Vt  = (__bf16*)(ws + (48u << 20));      // 8 MB  [b,h,64,s']
    __bf16* oh  = (__bf16*)(ws + (56u << 20));      // 8 MB  attention out [4096,1024]

    float* out  = (float*)d_out;
    float* attn = out + (size_t)MROWS * DMODEL;     // + 4,194,304

    ln_kernel<<<MROWS, 256, 0, stream>>>(query, lng, lnb, qn);
    cast_kernel<<<4096, 256, 0, stream>>>(key, kb);
    cast_kernel<<<4096, 256, 0, stream>>>(value, vb);
    cast_kernel<<<1024, 256, 0, stream>>>(w_q, wqb);
    cast_kernel<<<1024, 256, 0, stream>>>(w_k, wkb);
    cast_kernel<<<1024, 256, 0, stream>>>(w_v, wvb);
    cast_kernel<<<1024, 256, 0, stream>>>(w_o, wob);

    gemm_bt<0><<<256, 256, 0, stream>>>(qn, wqb, Qp, nullptr, MROWS, DMODEL);
    gemm_bt<1><<<256, 256, 0, stream>>>(kb, wkb, Kp, nullptr, MROWS, DMODEL);
    gemm_bt<2><<<256, 256, 0, stream>>>(vb, wvb, Vt, nullptr, MROWS, DMODEL);

    attn_kernel<<<MROWS, 256, 0, stream>>>(Qp, Kp, Vt, attn, oh);

    gemm_bt<3><<<256, 256, 0, stream>>>(oh, wob, d_out, query, MROWS, DMODEL);
}

// Round 2
// 428.461 us; speedup vs baseline: 1.2942x; 1.2942x over previous
//
#include <hip/hip_runtime.h>
#include <hip/hip_bf16.h>

// ---------------------------------------------------------------------------
// MultiheadAttention fused pipeline for MI355X (gfx950)
// B=2, S=S'=2048, H=16, D_MODEL=1024, dk=dv=64
// outputs: out [2,2048,1024] fp32, attn [2,16,2048,2048] fp32 (concat in d_out)
// ---------------------------------------------------------------------------

typedef __bf16 bf16x8 __attribute__((ext_vector_type(8)));
typedef __bf16 bf16x4 __attribute__((ext_vector_type(4)));
typedef float  f32x4  __attribute__((ext_vector_type(4)));
typedef float  f32x16 __attribute__((ext_vector_type(16)));

#define NUM_HEAD 16
#define SEQ 2048
#define DMODEL 1024
#define DK 64
#define MROWS 4096      // B*S

__device__ __forceinline__ void gload_lds16(const void* g, void* l) {
    __builtin_amdgcn_global_load_lds((const __attribute__((address_space(1))) void*)g,
                                     (__attribute__((address_space(3))) void*)l, 16, 0, 0);
}

// ---------------------------------------------------------------------------
// LayerNorm(query) -> bf16, one block (256 thr) per row of 1024
// ---------------------------------------------------------------------------
__global__ __launch_bounds__(256) void ln_kernel(const float* __restrict__ x,
                                                 const float* __restrict__ g,
                                                 const float* __restrict__ bt,
                                                 __bf16* __restrict__ y) {
    int row = blockIdx.x, tid = threadIdx.x;
    __shared__ float red[2][4];
    float4 v = ((const float4*)(x + (size_t)row * DMODEL))[tid];
    float s  = v.x + v.y + v.z + v.w;
    float sq = v.x * v.x + v.y * v.y + v.z * v.z + v.w * v.w;
    #pragma unroll
    for (int o = 32; o; o >>= 1) { s += __shfl_xor(s, o, 64); sq += __shfl_xor(sq, o, 64); }
    int wv = tid >> 6;
    if ((tid & 63) == 0) { red[0][wv] = s; red[1][wv] = sq; }
    __syncthreads();
    s  = red[0][0] + red[0][1] + red[0][2] + red[0][3];
    sq = red[1][0] + red[1][1] + red[1][2] + red[1][3];
    float mu  = s * (1.0f / DMODEL);
    float var = sq * (1.0f / DMODEL) - mu * mu;
    float rs  = rsqrtf(var + 1e-6f);
    float4 gg = ((const float4*)g)[tid];
    float4 bb = ((const float4*)bt)[tid];
    bf16x4 o;
    o[0] = (__bf16)((v.x - mu) * rs * gg.x + bb.x);
    o[1] = (__bf16)((v.y - mu) * rs * gg.y + bb.y);
    o[2] = (__bf16)((v.z - mu) * rs * gg.z + bb.z);
    o[3] = (__bf16)((v.w - mu) * rs * gg.w + bb.w);
    *(bf16x4*)&y[(size_t)row * DMODEL + tid * 4] = o;
}

// ---------------------------------------------------------------------------
// fp32 -> bf16 cast, 4 elems/thread
// ---------------------------------------------------------------------------
__global__ __launch_bounds__(256) void cast_kernel(const float* __restrict__ x,
                                                   __bf16* __restrict__ y) {
    int i = blockIdx.x * 256 + threadIdx.x;
    float4 v = ((const float4*)x)[i];
    bf16x4 o = {(__bf16)v.x, (__bf16)v.y, (__bf16)v.z, (__bf16)v.w};
    *(bf16x4*)&y[(size_t)i * 4] = o;
}

// ---------------------------------------------------------------------------
// GEMM C[M,N] = A[M,1024] * W^T  (W row-major [N,1024])
// 128x128 tile, 4 waves (2x2), 16x16x32 MFMA, global_load_lds staging.
// MODE 0: Q-proj  -> bf16 [b,h,s,64], scale 1/8 folded
// MODE 1: K-proj  -> bf16 [b,h,s,64]
// MODE 2: V-proj  -> bf16 [b,h,64,s']  (transposed for PV fragment loads)
// MODE 3: out-proj-> fp32 d_out + residual
// ---------------------------------------------------------------------------
template <int MODE>
__global__ __launch_bounds__(256) void gemm_bt(const __bf16* __restrict__ A,
                                               const __bf16* __restrict__ Bw,
                                               void* __restrict__ Cout,
                                               const float* __restrict__ residual,
                                               int M, int N) {
    const int Kd = 1024;
    __shared__ __bf16 As[128][32];
    __shared__ __bf16 Bs[128][32];
    int tiles_n = N >> 7;
    int tm = blockIdx.x / tiles_n, tn = blockIdx.x % tiles_n;
    int tid = threadIdx.x, lane = tid & 63, wv = tid >> 6;
    int wr = (wv >> 1) * 64, wc = (wv & 1) * 64;
    int lr = lane & 15, lg = lane >> 4;
    int r0 = tid >> 2, c0 = (tid & 3) * 8;   // staging: thread covers 8 bf16 (16B)

    f32x4 acc[4][4] = {};
    const __bf16* Arow = A  + (size_t)(tm * 128) * Kd;
    const __bf16* Brow = Bw + (size_t)(tn * 128) * Kd;

    for (int kt = 0; kt < Kd; kt += 32) {
        __syncthreads();   // previous iter's LDS reads done
        gload_lds16(&Arow[(size_t)r0 * Kd + kt + c0],        &As[r0][c0]);
        gload_lds16(&Arow[(size_t)(r0 + 64) * Kd + kt + c0], &As[r0 + 64][c0]);
        gload_lds16(&Brow[(size_t)r0 * Kd + kt + c0],        &Bs[r0][c0]);
        gload_lds16(&Brow[(size_t)(r0 + 64) * Kd + kt + c0], &Bs[r0 + 64][c0]);
        __syncthreads();   // drains vmcnt + lgkm
        bf16x8 af[4], bg[4];
        #pragma unroll
        for (int m = 0; m < 4; ++m) af[m] = *(bf16x8*)&As[wr + m * 16 + lr][lg * 8];
        #pragma unroll
        for (int n = 0; n < 4; ++n) bg[n] = *(bf16x8*)&Bs[wc + n * 16 + lr][lg * 8];
        #pragma unroll
        for (int m = 0; m < 4; ++m)
            #pragma unroll
            for (int n = 0; n < 4; ++n)
                acc[m][n] = __builtin_amdgcn_mfma_f32_16x16x32_bf16(af[m], bg[n], acc[m][n], 0, 0, 0);
    }

    #pragma unroll
    for (int m = 0; m < 4; ++m) {
        #pragma unroll
        for (int n = 0; n < 4; ++n) {
            #pragma unroll
            for (int r = 0; r < 4; ++r) {
                int grow = tm * 128 + wr + m * 16 + lg * 4 + r;
                int gcol = tn * 128 + wc + n * 16 + lr;
                float val = acc[m][n][r];
                if (MODE == 0) val *= 0.125f;  // 1/sqrt(dk)
                if (MODE == 0 || MODE == 1) {
                    int b = grow >> 11, ss = grow & 2047, h = gcol >> 6, d = gcol & 63;
                    ((__bf16*)Cout)[((size_t)(b * NUM_HEAD + h) * SEQ + ss) * DK + d] = (__bf16)val;
                } else if (MODE == 2) {
                    int b = grow >> 11, ss = grow & 2047, h = gcol >> 6, d = gcol & 63;
                    ((__bf16*)Cout)[((size_t)(b * NUM_HEAD + h) * DK + d) * SEQ + ss] = (__bf16)val;
                } else {
                    size_t idx = (size_t)grow * DMODEL + gcol;
                    ((float*)Cout)[idx] = val + residual[idx];
                }
            }
        }
    }
}

// ---------------------------------------------------------------------------
// Attention, flash-style two-phase, swapped QK^T (32x32x16 MFMA).
// Grid: bh(32) x qtile(64 of 32 rows) = 2048 blocks, 4 waves.
// Wave wv handles keys [wv*512, wv*512+512) for all 32 q-rows.
//   Phase A: online (m,l) in registers (lane&31 = q-row; halves hold
//            interleaved keys, merged once via shfl_xor(32)); cross-wave
//            merge via small LDS.
//   Phase B: recompute scores, P = exp(s-m)/l exactly; write P to global
//            via per-wave LDS transpose tile (coalesced 128B rows);
//            pack P->bf16 A-frags (shfl_xor(32) half exchange) and MFMA PV.
// O partials cross-wave reduced in LDS, written bf16 to out_heads.
// ---------------------------------------------------------------------------
__global__ __launch_bounds__(256) void attn_kernel(const __bf16* __restrict__ Qp,
                                                   const __bf16* __restrict__ Kp,
                                                   const __bf16* __restrict__ Vt,
                                                   float* __restrict__ attn_out,
                                                   __bf16* __restrict__ out_heads) {
    __shared__ float ored[4][32][68];    // O-reduce; front of each [wv] doubles as P-stage (32x36)
    __shared__ float mlred[4][32][2];

    int bid = blockIdx.x;
    int bh = bid >> 6;
    int qbase = (bid & 63) * 32;
    int tid = threadIdx.x, lane = tid & 63, wv = tid >> 6;
    int l31 = lane & 31, hi = lane >> 5;

    const __bf16* Qh = Qp + ((size_t)bh * SEQ + qbase) * DK;
    const __bf16* Kh = Kp + (size_t)bh * SEQ * DK;
    const __bf16* Vh = Vt + (size_t)bh * DK * SEQ;

    // Q fragments (B-operand): lane holds Q[q=l31][s*16 + hi*8 .. +8]
    bf16x8 qf[4];
    #pragma unroll
    for (int s = 0; s < 4; ++s)
        qf[s] = *(const bf16x8*)&Qh[(size_t)l31 * DK + s * 16 + hi * 8];

    int kbase = wv * 512;

    // ---- Phase A: online max / sum over this wave's 512 keys ----
    float m = -1e30f, lsum = 0.f;
    for (int t = 0; t < 16; ++t) {
        int k0 = kbase + t * 32;
        bf16x8 kf[4];
        #pragma unroll
        for (int s = 0; s < 4; ++s)
            kf[s] = *(const bf16x8*)&Kh[(size_t)(k0 + l31) * DK + s * 16 + hi * 8];
        f32x16 d;
        #pragma unroll
        for (int r = 0; r < 16; ++r) d[r] = 0.f;
        #pragma unroll
        for (int s = 0; s < 4; ++s)
            d = __builtin_amdgcn_mfma_f32_32x32x16_bf16(kf[s], qf[s], d, 0, 0, 0);
        float nm = m;
        #pragma unroll
        for (int r = 0; r < 16; ++r) nm = fmaxf(nm, d[r]);
        lsum *= __expf(m - nm);
        #pragma unroll
        for (int r = 0; r < 16; ++r) lsum += __expf(d[r] - nm);
        m = nm;
    }
    {   // merge the two interleaved key-halves (lane ^ 32, same q)
        float mo = __shfl_xor(m, 32, 64);
        float lo_ = __shfl_xor(lsum, 32, 64);
        float nm = fmaxf(m, mo);
        lsum = lsum * __expf(m - nm) + lo_ * __expf(mo - nm);
        m = nm;
    }
    if (hi == 0) { mlred[wv][l31][0] = m; mlred[wv][l31][1] = lsum; }
    __syncthreads();
    {   // merge across the 4 waves (each covered a disjoint 512-key range)
        float fm = -1e30f;
        #pragma unroll
        for (int w = 0; w < 4; ++w) fm = fmaxf(fm, mlred[w][l31][0]);
        float fl = 0.f;
        #pragma unroll
        for (int w = 0; w < 4; ++w) fl += mlred[w][l31][1] * __expf(mlred[w][l31][0] - fm);
        m = fm;
        lsum = fl;
    }
    float invl = 1.0f / lsum;

    // ---- Phase B: normalized P, global write, PV ----
    float* pst = &ored[wv][0][0];    // 32 rows x 36 floats staging (within ored[wv])
    float* attn_base = attn_out + ((size_t)bh * SEQ + qbase) * SEQ;
    f32x16 o0, o1;
    #pragma unroll
    for (int r = 0; r < 16; ++r) { o0[r] = 0.f; o1[r] = 0.f; }

    for (int t = 0; t < 16; ++t) {
        int k0 = kbase + t * 32;
        bf16x8 kf[4];
        #pragma unroll
        for (int s = 0; s < 4; ++s)
            kf[s] = *(const bf16x8*)&Kh[(size_t)(k0 + l31) * DK + s * 16 + hi * 8];
        f32x16 d;
        #pragma unroll
        for (int r = 0; r < 16; ++r) d[r] = 0.f;
        #pragma unroll
        for (int s = 0; s < 4; ++s)
            d = __builtin_amdgcn_mfma_f32_32x32x16_bf16(kf[s], qf[s], d, 0, 0, 0);

        float p[16];
        #pragma unroll
        for (int r = 0; r < 16; ++r) p[r] = __expf(d[r] - m) * invl;

        // stage to LDS transposed: row q=l31, col = key-in-tile
        // reg quad qd holds keys qd*8 + hi*4 .. +4
        #pragma unroll
        for (int qd = 0; qd < 4; ++qd) {
            f32x4 v4 = { p[4*qd], p[4*qd+1], p[4*qd+2], p[4*qd+3] };
            *(f32x4*)&pst[l31 * 36 + qd * 8 + hi * 4] = v4;
        }
        asm volatile("s_waitcnt lgkmcnt(0)" ::: "memory");
        {   // coalesced global write: lane covers 16 consecutive keys of one q-row
            int q = lane >> 1, cc = (lane & 1) * 16;
            #pragma unroll
            for (int j = 0; j < 4; ++j) {
                f32x4 v = *(f32x4*)&pst[q * 36 + cc + 4 * j];
                *(f32x4*)&attn_base[(size_t)q * SEQ + k0 + cc + 4 * j] = v;
            }
        }
        asm volatile("s_waitcnt lgkmcnt(0)" ::: "memory");

        // pack P to bf16 pair-words: w[i] = keys(reg 2i, 2i+1)
        unsigned int w[8];
        #pragma unroll
        for (int i = 0; i < 8; ++i) {
            union { __bf16 h[2]; unsigned int u; } bw;
            bw.h[0] = (__bf16)p[2*i];
            bw.h[1] = (__bf16)p[2*i+1];
            w[i] = bw.u;
        }
        #pragma unroll
        for (int slot = 0; slot < 2; ++slot) {
            unsigned int w0 = w[4*slot], w1 = w[4*slot+1], w2 = w[4*slot+2], w3 = w[4*slot+3];
            unsigned int s0 = (unsigned int)__shfl_xor((int)w0, 32, 64);
            unsigned int s1 = (unsigned int)__shfl_xor((int)w1, 32, 64);
            unsigned int s2 = (unsigned int)__shfl_xor((int)w2, 32, 64);
            unsigned int s3 = (unsigned int)__shfl_xor((int)w3, 32, 64);
            union { unsigned int u[4]; bf16x8 v; } pa;
            pa.u[0] = hi ? s2 : w0;   // lane<32: keys slot*16+0..7 ; lane>=32: +8..15
            pa.u[1] = hi ? s3 : w1;
            pa.u[2] = hi ? w2 : s0;
            pa.u[3] = hi ? w3 : s1;
            #pragma unroll
            for (int dvb = 0; dvb < 2; ++dvb) {
                bf16x8 vf = *(const bf16x8*)&Vh[(size_t)(dvb * 32 + l31) * SEQ + k0 + slot * 16 + hi * 8];
                if (dvb == 0) o0 = __builtin_amdgcn_mfma_f32_32x32x16_bf16(pa.v, vf, o0, 0, 0, 0);
                else          o1 = __builtin_amdgcn_mfma_f32_32x32x16_bf16(pa.v, vf, o1, 0, 0, 0);
            }
        }
    }

    // ---- store O partials to LDS, cross-wave reduce, write out_heads ----
    #pragma unroll
    for (int r = 0; r < 16; ++r) {
        int q = (r & 3) + 8 * (r >> 2) + 4 * hi;
        ored[wv][q][l31]      = o0[r];
        ored[wv][q][32 + l31] = o1[r];
    }
    __syncthreads();
    {
        int q = tid >> 3, d0 = (tid & 7) * 8;
        float s[8];
        #pragma unroll
        for (int j = 0; j < 8; ++j) s[j] = 0.f;
        #pragma unroll
        for (int w = 0; w < 4; ++w)
            #pragma unroll
            for (int j = 0; j < 8; ++j) s[j] += ored[w][q][d0 + j];
        int b = bh >> 4, h = bh & 15;
        bf16x8 ov;
        #pragma unroll
        for (int j = 0; j < 8; ++j) ov[j] = (__bf16)s[j];
        *(bf16x8*)&out_heads[((size_t)(b * SEQ + qbase + q)) * DMODEL + h * DK + d0] = ov;
    }
}

// ---------------------------------------------------------------------------
extern "C" void kernel_launch(void* const* d_in, const int* in_sizes, int n_in,
                              void* d_out, int out_size, void* d_ws, size_t ws_size,
                              hipStream_t stream) {
    const float* query = (const float*)d_in[0];
    const float* key   = (const float*)d_in[1];
    const float* value = (const float*)d_in[2];
    const float* w_q   = (const float*)d_in[3];
    const float* w_k   = (const float*)d_in[4];
    const float* w_v   = (const float*)d_in[5];
    const float* w_o   = (const float*)d_in[6];
    const float* lng   = (const float*)d_in[7];
    const float* lnb   = (const float*)d_in[8];

    char* ws = (char*)d_ws;
    __bf16* qn  = (__bf16*)(ws);                    // 8 MB  LN(query) bf16
    __bf16* kb  = (__bf16*)(ws + ( 8u << 20));      // 8 MB  key bf16
    __bf16* vb  = (__bf16*)(ws + (16u << 20));      // 8 MB  value bf16
    __bf16* wqb = (__bf16*)(ws + (24u << 20));      // 2 MB
    __bf16* wkb = (__bf16*)(ws + (26u << 20));      // 2 MB
    __bf16* wvb = (__bf16*)(ws + (28u << 20));      // 2 MB
    __bf16* wob = (__bf16*)(ws + (30u << 20));      // 2 MB
    __bf16* Qp  = (__bf16*)(ws + (32u << 20));      // 8 MB  [b,h,s,64] (x1/8)
    __bf16* Kp  = (__bf16*)(ws + (40u << 20));      // 8 MB  [b,h,s,64]
    __bf16* Vt  = (__bf16*)(ws + (48u << 20));      // 8 MB  [b,h,64,s']
    __bf16* oh  = (__bf16*)(ws + (56u << 20));      // 8 MB  attention out [4096,1024]

    float* out  = (float*)d_out;
    float* attn = out + (size_t)MROWS * DMODEL;

    ln_kernel<<<MROWS, 256, 0, stream>>>(query, lng, lnb, qn);
    cast_kernel<<<4096, 256, 0, stream>>>(key, kb);
    cast_kernel<<<4096, 256, 0, stream>>>(value, vb);
    cast_kernel<<<1024, 256, 0, stream>>>(w_q, wqb);
    cast_kernel<<<1024, 256, 0, stream>>>(w_k, wkb);
    cast_kernel<<<1024, 256, 0, stream>>>(w_v, wvb);
    cast_kernel<<<1024, 256, 0, stream>>>(w_o, wob);

    gemm_bt<0><<<256, 256, 0, stream>>>(qn, wqb, Qp, nullptr, MROWS, DMODEL);
    gemm_bt<1><<<256, 256, 0, stream>>>(kb, wkb, Kp, nullptr, MROWS, DMODEL);
    gemm_bt<2><<<256, 256, 0, stream>>>(vb, wvb, Vt, nullptr, MROWS, DMODEL);

    attn_kernel<<<2048, 256, 0, stream>>>(Qp, Kp, Vt, attn, oh);

    gemm_bt<3><<<256, 256, 0, stream>>>(oh, wob, d_out, query, MROWS, DMODEL);
}

// Round 5
// 386.446 us; speedup vs baseline: 1.4349x; 1.1087x over previous
//
#include <hip/hip_runtime.h>
#include <hip/hip_bf16.h>

// ---------------------------------------------------------------------------
// MultiheadAttention fused pipeline for MI355X (gfx950)
// B=2, S=S'=2048, H=16, D_MODEL=1024, dk=dv=64
// outputs: out [2,2048,1024] fp32, attn [2,16,2048,2048] fp32 (concat in d_out)
// ---------------------------------------------------------------------------

typedef __bf16 bf16x8 __attribute__((ext_vector_type(8)));
typedef __bf16 bf16x4 __attribute__((ext_vector_type(4)));
typedef float  f32x4  __attribute__((ext_vector_type(4)));
typedef float  f32x16 __attribute__((ext_vector_type(16)));

#define NUM_HEAD 16
#define SEQ 2048
#define DMODEL 1024
#define DK 64
#define MROWS 4096      // B*S

__device__ __forceinline__ void gload_lds16(const void* g, void* l) {
    __builtin_amdgcn_global_load_lds((const __attribute__((address_space(1))) void*)g,
                                     (__attribute__((address_space(3))) void*)l, 16, 0, 0);
}

// ---------------------------------------------------------------------------
// LayerNorm(query) -> bf16, one block (256 thr) per row of 1024
// ---------------------------------------------------------------------------
__global__ __launch_bounds__(256) void ln_kernel(const float* __restrict__ x,
                                                 const float* __restrict__ g,
                                                 const float* __restrict__ bt,
                                                 __bf16* __restrict__ y) {
    int row = blockIdx.x, tid = threadIdx.x;
    __shared__ float red[2][4];
    float4 v = ((const float4*)(x + (size_t)row * DMODEL))[tid];
    float s  = v.x + v.y + v.z + v.w;
    float sq = v.x * v.x + v.y * v.y + v.z * v.z + v.w * v.w;
    #pragma unroll
    for (int o = 32; o; o >>= 1) { s += __shfl_xor(s, o, 64); sq += __shfl_xor(sq, o, 64); }
    int wv = tid >> 6;
    if ((tid & 63) == 0) { red[0][wv] = s; red[1][wv] = sq; }
    __syncthreads();
    s  = red[0][0] + red[0][1] + red[0][2] + red[0][3];
    sq = red[1][0] + red[1][1] + red[1][2] + red[1][3];
    float mu  = s * (1.0f / DMODEL);
    float var = sq * (1.0f / DMODEL) - mu * mu;
    float rs  = rsqrtf(var + 1e-6f);
    float4 gg = ((const float4*)g)[tid];
    float4 bb = ((const float4*)bt)[tid];
    bf16x4 o;
    o[0] = (__bf16)((v.x - mu) * rs * gg.x + bb.x);
    o[1] = (__bf16)((v.y - mu) * rs * gg.y + bb.y);
    o[2] = (__bf16)((v.z - mu) * rs * gg.z + bb.z);
    o[3] = (__bf16)((v.w - mu) * rs * gg.w + bb.w);
    *(bf16x4*)&y[(size_t)row * DMODEL + tid * 4] = o;
}

// ---------------------------------------------------------------------------
// All fp32->bf16 casts in one dispatch (key, value, w_q, w_k, w_v, w_o).
// Thread i handles one float4. Total float4 count:
//   key 1048576 + value 1048576 + 4 x 262144 = 3145728  -> grid 12288.
// ---------------------------------------------------------------------------
__global__ __launch_bounds__(256) void cast_all(const float* __restrict__ key,
                                                const float* __restrict__ value,
                                                const float* __restrict__ wq,
                                                const float* __restrict__ wk,
                                                const float* __restrict__ wv,
                                                const float* __restrict__ wo,
                                                __bf16* kb, __bf16* vb, __bf16* wqb,
                                                __bf16* wkb, __bf16* wvb, __bf16* wob) {
    int i = blockIdx.x * 256 + threadIdx.x;     // float4 index, [0, 3145728)
    const float* src; __bf16* dst; int off;
    if (i < 1048576)      { src = key;   dst = kb;  off = i; }
    else if (i < 2097152) { src = value; dst = vb;  off = i - 1048576; }
    else if (i < 2359296) { src = wq;    dst = wqb; off = i - 2097152; }
    else if (i < 2621440) { src = wk;    dst = wkb; off = i - 2359296; }
    else if (i < 2883584) { src = wv;    dst = wvb; off = i - 2621440; }
    else                  { src = wo;    dst = wob; off = i - 2883584; }
    float4 v = ((const float4*)src)[off];
    bf16x4 o = {(__bf16)v.x, (__bf16)v.y, (__bf16)v.z, (__bf16)v.w};
    *(bf16x4*)&dst[(size_t)off * 4] = o;
}

// ---------------------------------------------------------------------------
// GEMM C[M,N] = A[M,1024] * W^T  (W row-major [N,1024])  -- round-2 verbatim
// 128x128 tile, 4 waves (2x2), 16x16x32 MFMA, global_load_lds staging.
// MODE 0: Q-proj  -> bf16 [b,h,s,64], scale 1/8 folded
// MODE 1: K-proj  -> bf16 [b,h,s,64]
// MODE 2: V-proj  -> bf16 [b,h,64,s']  (transposed for PV fragment loads)
// MODE 3: out-proj-> fp32 d_out + residual
// ---------------------------------------------------------------------------
template <int MODE>
__global__ __launch_bounds__(256) void gemm_bt(const __bf16* __restrict__ A,
                                               const __bf16* __restrict__ Bw,
                                               void* __restrict__ Cout,
                                               const float* __restrict__ residual,
                                               int M, int N) {
    const int Kd = 1024;
    __shared__ __bf16 As[128][32];
    __shared__ __bf16 Bs[128][32];
    int tiles_n = N >> 7;
    int tm = blockIdx.x / tiles_n, tn = blockIdx.x % tiles_n;
    int tid = threadIdx.x, lane = tid & 63, wv = tid >> 6;
    int wr = (wv >> 1) * 64, wc = (wv & 1) * 64;
    int lr = lane & 15, lg = lane >> 4;
    int r0 = tid >> 2, c0 = (tid & 3) * 8;   // staging: thread covers 8 bf16 (16B)

    f32x4 acc[4][4] = {};
    const __bf16* Arow = A  + (size_t)(tm * 128) * Kd;
    const __bf16* Brow = Bw + (size_t)(tn * 128) * Kd;

    for (int kt = 0; kt < Kd; kt += 32) {
        __syncthreads();   // previous iter's LDS reads done
        gload_lds16(&Arow[(size_t)r0 * Kd + kt + c0],        &As[r0][c0]);
        gload_lds16(&Arow[(size_t)(r0 + 64) * Kd + kt + c0], &As[r0 + 64][c0]);
        gload_lds16(&Brow[(size_t)r0 * Kd + kt + c0],        &Bs[r0][c0]);
        gload_lds16(&Brow[(size_t)(r0 + 64) * Kd + kt + c0], &Bs[r0 + 64][c0]);
        __syncthreads();   // drains vmcnt + lgkm
        bf16x8 af[4], bg[4];
        #pragma unroll
        for (int m = 0; m < 4; ++m) af[m] = *(bf16x8*)&As[wr + m * 16 + lr][lg * 8];
        #pragma unroll
        for (int n = 0; n < 4; ++n) bg[n] = *(bf16x8*)&Bs[wc + n * 16 + lr][lg * 8];
        #pragma unroll
        for (int m = 0; m < 4; ++m)
            #pragma unroll
            for (int n = 0; n < 4; ++n)
                acc[m][n] = __builtin_amdgcn_mfma_f32_16x16x32_bf16(af[m], bg[n], acc[m][n], 0, 0, 0);
    }

    #pragma unroll
    for (int m = 0; m < 4; ++m) {
        #pragma unroll
        for (int n = 0; n < 4; ++n) {
            #pragma unroll
            for (int r = 0; r < 4; ++r) {
                int grow = tm * 128 + wr + m * 16 + lg * 4 + r;
                int gcol = tn * 128 + wc + n * 16 + lr;
                float val = acc[m][n][r];
                if (MODE == 0) val *= 0.125f;  // 1/sqrt(dk)
                if (MODE == 0 || MODE == 1) {
                    int b = grow >> 11, ss = grow & 2047, h = gcol >> 6, d = gcol & 63;
                    ((__bf16*)Cout)[((size_t)(b * NUM_HEAD + h) * SEQ + ss) * DK + d] = (__bf16)val;
                } else if (MODE == 2) {
                    int b = grow >> 11, ss = grow & 2047, h = gcol >> 6, d = gcol & 63;
                    ((__bf16*)Cout)[((size_t)(b * NUM_HEAD + h) * DK + d) * SEQ + ss] = (__bf16)val;
                } else {
                    size_t idx = (size_t)grow * DMODEL + gcol;
                    ((float*)Cout)[idx] = val + residual[idx];
                }
            }
        }
    }
}

// ---------------------------------------------------------------------------
// Attention, flash-style two-phase, swapped QK^T (32x32x16 MFMA).
// Grid 2048 blocks (XCD-chunked swizzle: each XCD keeps 4 heads' K/V in L2),
// 4 waves; wave wv owns keys [wv*512, wv*512+512) for the block's 32 q-rows.
// Phase A: online (m,l) in regs, tree max + defer-max (T13); merge via
//          shfl_xor(32) + small LDS across waves.
// Phase B: recompute scores, P=exp(s-m)/l, write P DIRECT from regs
//          (reg quad = 4 consecutive keys -> f32x4 stores), pack to bf16
//          A-frags via shfl_xor(32), MFMA PV. Cross-wave O reduce in LDS.
// ---------------------------------------------------------------------------
__global__ __launch_bounds__(256) void attn_kernel(const __bf16* __restrict__ Qp,
                                                   const __bf16* __restrict__ Kp,
                                                   const __bf16* __restrict__ Vt,
                                                   float* __restrict__ attn_out,
                                                   __bf16* __restrict__ out_heads) {
    __shared__ float ored[4][32][68];
    __shared__ float mlred[4][32][2];

    int bid = blockIdx.x;
    int wid = (bid & 7) * 256 + (bid >> 3);   // XCD-chunked: each XCD gets 4 heads
    int bh = wid >> 6;
    int qbase = (wid & 63) * 32;
    int tid = threadIdx.x, lane = tid & 63, wv = tid >> 6;
    int l31 = lane & 31, hi = lane >> 5;

    const __bf16* Qh = Qp + ((size_t)bh * SEQ + qbase) * DK;
    const __bf16* Kh = Kp + (size_t)bh * SEQ * DK;
    const __bf16* Vh = Vt + (size_t)bh * DK * SEQ;

    bf16x8 qf[4];
    #pragma unroll
    for (int s = 0; s < 4; ++s)
        qf[s] = *(const bf16x8*)&Qh[(size_t)l31 * DK + s * 16 + hi * 8];

    int kbase = wv * 512;

    // ---- Phase A: online max / sum over this wave's 512 keys ----
    float m = -1e30f, lsum = 0.f;
    for (int t = 0; t < 16; ++t) {
        int k0 = kbase + t * 32;
        bf16x8 kf[4];
        #pragma unroll
        for (int s = 0; s < 4; ++s)
            kf[s] = *(const bf16x8*)&Kh[(size_t)(k0 + l31) * DK + s * 16 + hi * 8];
        f32x16 d;
        #pragma unroll
        for (int r = 0; r < 16; ++r) d[r] = 0.f;
        #pragma unroll
        for (int s = 0; s < 4; ++s)
            d = __builtin_amdgcn_mfma_f32_32x32x16_bf16(kf[s], qf[s], d, 0, 0, 0);
        float m8[8];
        #pragma unroll
        for (int r = 0; r < 8; ++r) m8[r] = fmaxf(d[r], d[r + 8]);
        #pragma unroll
        for (int r = 0; r < 4; ++r) m8[r] = fmaxf(m8[r], m8[r + 4]);
        float pmax = fmaxf(fmaxf(m8[0], m8[1]), fmaxf(m8[2], m8[3]));
        if (!__all(pmax - m <= 8.0f)) {    // defer-max: rescale rarely
            float nm = fmaxf(m, pmax);
            lsum *= __expf(m - nm);
            m = nm;
        }
        float es[4] = {0.f, 0.f, 0.f, 0.f};
        #pragma unroll
        for (int r = 0; r < 16; ++r) es[r & 3] += __expf(d[r] - m);
        lsum += (es[0] + es[1]) + (es[2] + es[3]);
    }
    {   // merge interleaved key-halves (lane ^ 32, same q)
        float mo = __shfl_xor(m, 32, 64);
        float lo_ = __shfl_xor(lsum, 32, 64);
        float nm = fmaxf(m, mo);
        lsum = lsum * __expf(m - nm) + lo_ * __expf(mo - nm);
        m = nm;
    }
    if (hi == 0) { mlred[wv][l31][0] = m; mlred[wv][l31][1] = lsum; }
    __syncthreads();
    {   // merge across 4 waves (disjoint key ranges)
        float fm = -1e30f;
        #pragma unroll
        for (int w = 0; w < 4; ++w) fm = fmaxf(fm, mlred[w][l31][0]);
        float fl = 0.f;
        #pragma unroll
        for (int w = 0; w < 4; ++w) fl += mlred[w][l31][1] * __expf(mlred[w][l31][0] - fm);
        m = fm;
        lsum = fl;
    }
    float invl = 1.0f / lsum;

    // ---- Phase B: normalized P, direct global write, PV ----
    float* attn_base = attn_out + ((size_t)bh * SEQ + qbase) * SEQ;
    f32x16 o0, o1;
    #pragma unroll
    for (int r = 0; r < 16; ++r) { o0[r] = 0.f; o1[r] = 0.f; }

    for (int t = 0; t < 16; ++t) {
        int k0 = kbase + t * 32;
        bf16x8 kf[4];
        #pragma unroll
        for (int s = 0; s < 4; ++s)
            kf[s] = *(const bf16x8*)&Kh[(size_t)(k0 + l31) * DK + s * 16 + hi * 8];
        f32x16 d;
        #pragma unroll
        for (int r = 0; r < 16; ++r) d[r] = 0.f;
        #pragma unroll
        for (int s = 0; s < 4; ++s)
            d = __builtin_amdgcn_mfma_f32_32x32x16_bf16(kf[s], qf[s], d, 0, 0, 0);

        #pragma unroll
        for (int r = 0; r < 16; ++r) d[r] = __expf(d[r] - m) * invl;

        // direct P write: reg quad q4 = keys k0 + 8*q4 + 4*hi + (0..3), row q=l31
        #pragma unroll
        for (int q4 = 0; q4 < 4; ++q4) {
            f32x4 v4 = {d[4 * q4], d[4 * q4 + 1], d[4 * q4 + 2], d[4 * q4 + 3]};
            *(f32x4*)&attn_base[(size_t)l31 * SEQ + k0 + 8 * q4 + 4 * hi] = v4;
        }

        // pack P to bf16 pair-words: w[i] = keys(reg 2i, 2i+1)
        unsigned int w[8];
        #pragma unroll
        for (int i = 0; i < 8; ++i) {
            union { __bf16 h[2]; unsigned int u; } bw;
            bw.h[0] = (__bf16)d[2 * i];
            bw.h[1] = (__bf16)d[2 * i + 1];
            w[i] = bw.u;
        }
        #pragma unroll
        for (int slot = 0; slot < 2; ++slot) {
            unsigned int w0 = w[4 * slot], w1 = w[4 * slot + 1], w2 = w[4 * slot + 2], w3 = w[4 * slot + 3];
            unsigned int s0 = (unsigned int)__shfl_xor((int)w0, 32, 64);
            unsigned int s1 = (unsigned int)__shfl_xor((int)w1, 32, 64);
            unsigned int s2 = (unsigned int)__shfl_xor((int)w2, 32, 64);
            unsigned int s3 = (unsigned int)__shfl_xor((int)w3, 32, 64);
            union { unsigned int u[4]; bf16x8 v; } pa;
            pa.u[0] = hi ? s2 : w0;
            pa.u[1] = hi ? s3 : w1;
            pa.u[2] = hi ? w2 : s0;
            pa.u[3] = hi ? w3 : s1;
            #pragma unroll
            for (int dvb = 0; dvb < 2; ++dvb) {
                bf16x8 vf = *(const bf16x8*)&Vh[(size_t)(dvb * 32 + l31) * SEQ + k0 + slot * 16 + hi * 8];
                if (dvb == 0) o0 = __builtin_amdgcn_mfma_f32_32x32x16_bf16(pa.v, vf, o0, 0, 0, 0);
                else          o1 = __builtin_amdgcn_mfma_f32_32x32x16_bf16(pa.v, vf, o1, 0, 0, 0);
            }
        }
    }

    // ---- cross-wave O reduce, write out_heads ----
    #pragma unroll
    for (int r = 0; r < 16; ++r) {
        int q = (r & 3) + 8 * (r >> 2) + 4 * hi;
        ored[wv][q][l31]      = o0[r];
        ored[wv][q][32 + l31] = o1[r];
    }
    __syncthreads();
    {
        int q = tid >> 3, d0 = (tid & 7) * 8;
        float s[8];
        #pragma unroll
        for (int j = 0; j < 8; ++j) s[j] = 0.f;
        #pragma unroll
        for (int w = 0; w < 4; ++w)
            #pragma unroll
            for (int j = 0; j < 8; ++j) s[j] += ored[w][q][d0 + j];
        int b = bh >> 4, h = bh & 15;
        bf16x8 ov;
        #pragma unroll
        for (int j = 0; j < 8; ++j) ov[j] = (__bf16)s[j];
        *(bf16x8*)&out_heads[((size_t)(b * SEQ + qbase + q)) * DMODEL + h * DK + d0] = ov;
    }
}

// ---------------------------------------------------------------------------
extern "C" void kernel_launch(void* const* d_in, const int* in_sizes, int n_in,
                              void* d_out, int out_size, void* d_ws, size_t ws_size,
                              hipStream_t stream) {
    const float* query = (const float*)d_in[0];
    const float* key   = (const float*)d_in[1];
    const float* value = (const float*)d_in[2];
    const float* w_q   = (const float*)d_in[3];
    const float* w_k   = (const float*)d_in[4];
    const float* w_v   = (const float*)d_in[5];
    const float* w_o   = (const float*)d_in[6];
    const float* lng   = (const float*)d_in[7];
    const float* lnb   = (const float*)d_in[8];

    char* ws = (char*)d_ws;
    __bf16* qn  = (__bf16*)(ws);                    // 8 MB  LN(query) bf16
    __bf16* kb  = (__bf16*)(ws + ( 8u << 20));      // 8 MB  key bf16
    __bf16* vb  = (__bf16*)(ws + (16u << 20));      // 8 MB  value bf16
    __bf16* wqb = (__bf16*)(ws + (24u << 20));      // 2 MB
    __bf16* wkb = (__bf16*)(ws + (26u << 20));      // 2 MB
    __bf16* wvb = (__bf16*)(ws + (28u << 20));      // 2 MB
    __bf16* wob = (__bf16*)(ws + (30u << 20));      // 2 MB
    __bf16* Qp  = (__bf16*)(ws + (32u << 20));      // 8 MB  [b,h,s,64] (x1/8)
    __bf16* Kp  = (__bf16*)(ws + (40u << 20));      // 8 MB  [b,h,s,64]
    __bf16* Vt  = (__bf16*)(ws + (48u << 20));      // 8 MB  [b,h,64,s']
    __bf16* oh  = (__bf16*)(ws + (56u << 20));      // 8 MB  attention out [4096,1024]

    float* out  = (float*)d_out;
    float* attn = out + (size_t)MROWS * DMODEL;

    ln_kernel<<<MROWS, 256, 0, stream>>>(query, lng, lnb, qn);
    cast_all<<<12288, 256, 0, stream>>>(key, value, w_q, w_k, w_v, w_o,
                                        kb, vb, wqb, wkb, wvb, wob);

    gemm_bt<0><<<256, 256, 0, stream>>>(qn, wqb, Qp, nullptr, MROWS, DMODEL);
    gemm_bt<1><<<256, 256, 0, stream>>>(kb, wkb, Kp, nullptr, MROWS, DMODEL);
    gemm_bt<2><<<256, 256, 0, stream>>>(vb, wvb, Vt, nullptr, MROWS, DMODEL);

    attn_kernel<<<2048, 256, 0, stream>>>(Qp, Kp, Vt, attn, oh);

    gemm_bt<3><<<256, 256, 0, stream>>>(oh, wob, d_out, query, MROWS, DMODEL);
}

// Round 6
// 386.275 us; speedup vs baseline: 1.4356x; 1.0004x over previous
//
#include <hip/hip_runtime.h>
#include <hip/hip_bf16.h>

// ---------------------------------------------------------------------------
// MultiheadAttention fused pipeline for MI355X (gfx950)
// B=2, S=S'=2048, H=16, D_MODEL=1024, dk=dv=64
// outputs: out [2,2048,1024] fp32, attn [2,16,2048,2048] fp32 (concat in d_out)
// ---------------------------------------------------------------------------

typedef __bf16 bf16x8 __attribute__((ext_vector_type(8)));
typedef __bf16 bf16x4 __attribute__((ext_vector_type(4)));
typedef float  f32x4  __attribute__((ext_vector_type(4)));
typedef float  f32x16 __attribute__((ext_vector_type(16)));

#define NUM_HEAD 16
#define SEQ 2048
#define DMODEL 1024
#define DK 64
#define MROWS 4096      // B*S

__device__ __forceinline__ void gload_lds16(const void* g, void* l) {
    __builtin_amdgcn_global_load_lds((const __attribute__((address_space(1))) void*)g,
                                     (__attribute__((address_space(3))) void*)l, 16, 0, 0);
}

// ---------------------------------------------------------------------------
// LayerNorm(query) -> bf16, one block (256 thr) per row of 1024
// ---------------------------------------------------------------------------
__global__ __launch_bounds__(256) void ln_kernel(const float* __restrict__ x,
                                                 const float* __restrict__ g,
                                                 const float* __restrict__ bt,
                                                 __bf16* __restrict__ y) {
    int row = blockIdx.x, tid = threadIdx.x;
    __shared__ float red[2][4];
    float4 v = ((const float4*)(x + (size_t)row * DMODEL))[tid];
    float s  = v.x + v.y + v.z + v.w;
    float sq = v.x * v.x + v.y * v.y + v.z * v.z + v.w * v.w;
    #pragma unroll
    for (int o = 32; o; o >>= 1) { s += __shfl_xor(s, o, 64); sq += __shfl_xor(sq, o, 64); }
    int wv = tid >> 6;
    if ((tid & 63) == 0) { red[0][wv] = s; red[1][wv] = sq; }
    __syncthreads();
    s  = red[0][0] + red[0][1] + red[0][2] + red[0][3];
    sq = red[1][0] + red[1][1] + red[1][2] + red[1][3];
    float mu  = s * (1.0f / DMODEL);
    float var = sq * (1.0f / DMODEL) - mu * mu;
    float rs  = rsqrtf(var + 1e-6f);
    float4 gg = ((const float4*)g)[tid];
    float4 bb = ((const float4*)bt)[tid];
    bf16x4 o;
    o[0] = (__bf16)((v.x - mu) * rs * gg.x + bb.x);
    o[1] = (__bf16)((v.y - mu) * rs * gg.y + bb.y);
    o[2] = (__bf16)((v.z - mu) * rs * gg.z + bb.z);
    o[3] = (__bf16)((v.w - mu) * rs * gg.w + bb.w);
    *(bf16x4*)&y[(size_t)row * DMODEL + tid * 4] = o;
}

// ---------------------------------------------------------------------------
// All fp32->bf16 casts in one dispatch.  Total float4 = 3,145,728 -> grid 12288.
// ---------------------------------------------------------------------------
__global__ __launch_bounds__(256) void cast_all(const float* __restrict__ key,
                                                const float* __restrict__ value,
                                                const float* __restrict__ wq,
                                                const float* __restrict__ wk,
                                                const float* __restrict__ wv,
                                                const float* __restrict__ wo,
                                                __bf16* kb, __bf16* vb, __bf16* wqb,
                                                __bf16* wkb, __bf16* wvb, __bf16* wob) {
    int i = blockIdx.x * 256 + threadIdx.x;     // float4 index, [0, 3145728)
    const float* src; __bf16* dst; int off;
    if (i < 1048576)      { src = key;   dst = kb;  off = i; }
    else if (i < 2097152) { src = value; dst = vb;  off = i - 1048576; }
    else if (i < 2359296) { src = wq;    dst = wqb; off = i - 2097152; }
    else if (i < 2621440) { src = wk;    dst = wkb; off = i - 2359296; }
    else if (i < 2883584) { src = wv;    dst = wvb; off = i - 2621440; }
    else                  { src = wo;    dst = wob; off = i - 2883584; }
    float4 v = ((const float4*)src)[off];
    bf16x4 o = {(__bf16)v.x, (__bf16)v.y, (__bf16)v.z, (__bf16)v.w};
    *(bf16x4*)&dst[(size_t)off * 4] = o;
}

// ---------------------------------------------------------------------------
// Fused Q/K/V projections. 768 blocks (3 modes x 256 tiles) -> 3 blocks/CU.
// Body identical to the verified gemm_bt; mode selected at runtime.
// mode 0: Q -> bf16 [b,h,s,64] scaled 1/8; mode 1: K -> [b,h,s,64];
// mode 2: V -> [b,h,64,s'] transposed.
// ---------------------------------------------------------------------------
__global__ __launch_bounds__(256) void qkv_proj(const __bf16* __restrict__ qn,
                                                const __bf16* __restrict__ kb,
                                                const __bf16* __restrict__ vb,
                                                const __bf16* __restrict__ wqb,
                                                const __bf16* __restrict__ wkb,
                                                const __bf16* __restrict__ wvb,
                                                __bf16* __restrict__ Qp,
                                                __bf16* __restrict__ Kp,
                                                __bf16* __restrict__ Vt) {
    const int Kd = 1024;
    __shared__ __bf16 As[128][32];
    __shared__ __bf16 Bs[128][32];
    int mode = blockIdx.x >> 8;               // 0,1,2
    int t = blockIdx.x & 255;
    int tm = t >> 3, tn = t & 7;              // 32 x 8 tiles (N=1024)
    int tid = threadIdx.x, lane = tid & 63, wv = tid >> 6;
    int wr = (wv >> 1) * 64, wc = (wv & 1) * 64;
    int lr = lane & 15, lg = lane >> 4;
    int r0 = tid >> 2, c0 = (tid & 3) * 8;

    const __bf16* A = (mode == 0) ? qn : (mode == 1) ? kb : vb;
    const __bf16* W = (mode == 0) ? wqb : (mode == 1) ? wkb : wvb;

    f32x4 acc[4][4] = {};
    const __bf16* Arow = A + (size_t)(tm * 128) * Kd;
    const __bf16* Brow = W + (size_t)(tn * 128) * Kd;

    for (int kt = 0; kt < Kd; kt += 32) {
        __syncthreads();
        gload_lds16(&Arow[(size_t)r0 * Kd + kt + c0],        &As[r0][c0]);
        gload_lds16(&Arow[(size_t)(r0 + 64) * Kd + kt + c0], &As[r0 + 64][c0]);
        gload_lds16(&Brow[(size_t)r0 * Kd + kt + c0],        &Bs[r0][c0]);
        gload_lds16(&Brow[(size_t)(r0 + 64) * Kd + kt + c0], &Bs[r0 + 64][c0]);
        __syncthreads();
        bf16x8 af[4], bg[4];
        #pragma unroll
        for (int m = 0; m < 4; ++m) af[m] = *(bf16x8*)&As[wr + m * 16 + lr][lg * 8];
        #pragma unroll
        for (int n = 0; n < 4; ++n) bg[n] = *(bf16x8*)&Bs[wc + n * 16 + lr][lg * 8];
        #pragma unroll
        for (int m = 0; m < 4; ++m)
            #pragma unroll
            for (int n = 0; n < 4; ++n)
                acc[m][n] = __builtin_amdgcn_mfma_f32_16x16x32_bf16(af[m], bg[n], acc[m][n], 0, 0, 0);
    }

    if (mode < 2) {
        float scale = (mode == 0) ? 0.125f : 1.0f;
        __bf16* C = (mode == 0) ? Qp : Kp;
        #pragma unroll
        for (int m = 0; m < 4; ++m)
            #pragma unroll
            for (int n = 0; n < 4; ++n)
                #pragma unroll
                for (int r = 0; r < 4; ++r) {
                    int grow = tm * 128 + wr + m * 16 + lg * 4 + r;
                    int gcol = tn * 128 + wc + n * 16 + lr;
                    int b = grow >> 11, ss = grow & 2047, h = gcol >> 6, d = gcol & 63;
                    C[((size_t)(b * NUM_HEAD + h) * SEQ + ss) * DK + d] = (__bf16)(acc[m][n][r] * scale);
                }
    } else {
        #pragma unroll
        for (int m = 0; m < 4; ++m)
            #pragma unroll
            for (int n = 0; n < 4; ++n)
                #pragma unroll
                for (int r = 0; r < 4; ++r) {
                    int grow = tm * 128 + wr + m * 16 + lg * 4 + r;
                    int gcol = tn * 128 + wc + n * 16 + lr;
                    int b = grow >> 11, ss = grow & 2047, h = gcol >> 6, d = gcol & 63;
                    Vt[((size_t)(b * NUM_HEAD + h) * DK + d) * SEQ + ss] = (__bf16)acc[m][n][r];
                }
    }
}

// ---------------------------------------------------------------------------
// Output projection + residual (verified gemm_bt MODE 3), 256 blocks.
// ---------------------------------------------------------------------------
__global__ __launch_bounds__(256) void out_gemm(const __bf16* __restrict__ A,
                                                const __bf16* __restrict__ Bw,
                                                const float* __restrict__ residual,
                                                float* __restrict__ out) {
    const int Kd = 1024;
    __shared__ __bf16 As[128][32];
    __shared__ __bf16 Bs[128][32];
    int tm = blockIdx.x >> 3, tn = blockIdx.x & 7;
    int tid = threadIdx.x, lane = tid & 63, wv = tid >> 6;
    int wr = (wv >> 1) * 64, wc = (wv & 1) * 64;
    int lr = lane & 15, lg = lane >> 4;
    int r0 = tid >> 2, c0 = (tid & 3) * 8;

    f32x4 acc[4][4] = {};
    const __bf16* Arow = A  + (size_t)(tm * 128) * Kd;
    const __bf16* Brow = Bw + (size_t)(tn * 128) * Kd;

    for (int kt = 0; kt < Kd; kt += 32) {
        __syncthreads();
        gload_lds16(&Arow[(size_t)r0 * Kd + kt + c0],        &As[r0][c0]);
        gload_lds16(&Arow[(size_t)(r0 + 64) * Kd + kt + c0], &As[r0 + 64][c0]);
        gload_lds16(&Brow[(size_t)r0 * Kd + kt + c0],        &Bs[r0][c0]);
        gload_lds16(&Brow[(size_t)(r0 + 64) * Kd + kt + c0], &Bs[r0 + 64][c0]);
        __syncthreads();
        bf16x8 af[4], bg[4];
        #pragma unroll
        for (int m = 0; m < 4; ++m) af[m] = *(bf16x8*)&As[wr + m * 16 + lr][lg * 8];
        #pragma unroll
        for (int n = 0; n < 4; ++n) bg[n] = *(bf16x8*)&Bs[wc + n * 16 + lr][lg * 8];
        #pragma unroll
        for (int m = 0; m < 4; ++m)
            #pragma unroll
            for (int n = 0; n < 4; ++n)
                acc[m][n] = __builtin_amdgcn_mfma_f32_16x16x32_bf16(af[m], bg[n], acc[m][n], 0, 0, 0);
    }

    #pragma unroll
    for (int m = 0; m < 4; ++m)
        #pragma unroll
        for (int n = 0; n < 4; ++n)
            #pragma unroll
            for (int r = 0; r < 4; ++r) {
                int grow = tm * 128 + wr + m * 16 + lg * 4 + r;
                int gcol = tn * 128 + wc + n * 16 + lr;
                size_t idx = (size_t)grow * DMODEL + gcol;
                out[idx] = acc[m][n][r] + residual[idx];
            }
}

// ---------------------------------------------------------------------------
// Attention, SINGLE-PASS register-resident scores, swapped QK^T (32x32x16).
// Grid 2048 blocks (XCD-chunked) x 512 threads (8 waves).
// Wave wv owns keys [wv*256, wv*256+256) for the block's 32 q-rows:
//   scores f32x16 d[8] (128 VGPR). Exact 2-stage softmax:
//   per-wave raw max -> LDS -> global max; one exp pass + sum -> LDS -> l.
//   Then per 32-key tile: direct P write from regs + bf16 pack + PV MFMA
//   (per-tile code verbatim from the verified round-5 phase B).
// O partials cross-wave reduced in LDS.
// ---------------------------------------------------------------------------
__global__ __launch_bounds__(512) void attn_kernel(const __bf16* __restrict__ Qp,
                                                   const __bf16* __restrict__ Kp,
                                                   const __bf16* __restrict__ Vt,
                                                   float* __restrict__ attn_out,
                                                   __bf16* __restrict__ out_heads) {
    __shared__ float ored[8][32][68];   // 69,632 B
    __shared__ float mred[8][32];
    __shared__ float lred[8][32];

    int bid = blockIdx.x;
    int wid = (bid & 7) * 256 + (bid >> 3);   // XCD-chunked
    int bh = wid >> 6;
    int qbase = (wid & 63) * 32;
    int tid = threadIdx.x, lane = tid & 63, wv = tid >> 6;   // wv in [0,8)
    int l31 = lane & 31, hi = lane >> 5;

    const __bf16* Qh = Qp + ((size_t)bh * SEQ + qbase) * DK;
    const __bf16* Kh = Kp + (size_t)bh * SEQ * DK;
    const __bf16* Vh = Vt + (size_t)bh * DK * SEQ;

    bf16x8 qf[4];
    #pragma unroll
    for (int s = 0; s < 4; ++s)
        qf[s] = *(const bf16x8*)&Qh[(size_t)l31 * DK + s * 16 + hi * 8];

    int kbase = wv * 256;

    // ---- QK^T: all 8 tiles, scores stay in registers ----
    f32x16 d[8];
    #pragma unroll
    for (int t = 0; t < 8; ++t) {
        int k0 = kbase + t * 32;
        bf16x8 kf[4];
        #pragma unroll
        for (int s = 0; s < 4; ++s)
            kf[s] = *(const bf16x8*)&Kh[(size_t)(k0 + l31) * DK + s * 16 + hi * 8];
        f32x16 acc;
        #pragma unroll
        for (int r = 0; r < 16; ++r) acc[r] = 0.f;
        #pragma unroll
        for (int s = 0; s < 4; ++s)
            acc = __builtin_amdgcn_mfma_f32_32x32x16_bf16(kf[s], qf[s], acc, 0, 0, 0);
        d[t] = acc;
    }

    // ---- stage 1: global max for q-row l31 ----
    f32x16 mv = d[0];
    #pragma unroll
    for (int t = 1; t < 8; ++t)
        #pragma unroll
        for (int r = 0; r < 16; ++r) mv[r] = fmaxf(mv[r], d[t][r]);
    float m8[8];
    #pragma unroll
    for (int r = 0; r < 8; ++r) m8[r] = fmaxf(mv[r], mv[r + 8]);
    #pragma unroll
    for (int r = 0; r < 4; ++r) m8[r] = fmaxf(m8[r], m8[r + 4]);
    float mx = fmaxf(fmaxf(m8[0], m8[1]), fmaxf(m8[2], m8[3]));
    mx = fmaxf(mx, __shfl_xor(mx, 32, 64));
    if (hi == 0) mred[wv][l31] = mx;
    __syncthreads();
    float m = mred[0][l31];
    #pragma unroll
    for (int w = 1; w < 8; ++w) m = fmaxf(m, mred[w][l31]);

    // ---- stage 2: exp in place + row sum ----
    f32x16 sv;
    #pragma unroll
    for (int r = 0; r < 16; ++r) sv[r] = 0.f;
    #pragma unroll
    for (int t = 0; t < 8; ++t)
        #pragma unroll
        for (int r = 0; r < 16; ++r) {
            float e = __expf(d[t][r] - m);
            d[t][r] = e;
            sv[r] += e;
        }
    float s8[8];
    #pragma unroll
    for (int r = 0; r < 8; ++r) s8[r] = sv[r] + sv[r + 8];
    #pragma unroll
    for (int r = 0; r < 4; ++r) s8[r] = s8[r] + s8[r + 4];
    float ls = (s8[0] + s8[1]) + (s8[2] + s8[3]);
    ls += __shfl_xor(ls, 32, 64);
    if (hi == 0) lred[wv][l31] = ls;
    __syncthreads();
    float lsum = 0.f;
    #pragma unroll
    for (int w = 0; w < 8; ++w) lsum += lred[w][l31];
    float invl = 1.0f / lsum;

    // ---- per tile: direct P write + pack + PV (verified structure) ----
    float* attn_base = attn_out + ((size_t)bh * SEQ + qbase) * SEQ;
    f32x16 o0, o1;
    #pragma unroll
    for (int r = 0; r < 16; ++r) { o0[r] = 0.f; o1[r] = 0.f; }

    #pragma unroll
    for (int t = 0; t < 8; ++t) {
        int k0 = kbase + t * 32;
        float p[16];
        #pragma unroll
        for (int r = 0; r < 16; ++r) p[r] = d[t][r] * invl;

        // direct P write: reg quad q4 = keys k0 + 8*q4 + 4*hi + (0..3), row q=l31
        #pragma unroll
        for (int q4 = 0; q4 < 4; ++q4) {
            f32x4 v4 = {p[4 * q4], p[4 * q4 + 1], p[4 * q4 + 2], p[4 * q4 + 3]};
            *(f32x4*)&attn_base[(size_t)l31 * SEQ + k0 + 8 * q4 + 4 * hi] = v4;
        }

        // pack P to bf16 pair-words: w[i] = keys(reg 2i, 2i+1)
        unsigned int w[8];
        #pragma unroll
        for (int i = 0; i < 8; ++i) {
            union { __bf16 h[2]; unsigned int u; } bw;
            bw.h[0] = (__bf16)p[2 * i];
            bw.h[1] = (__bf16)p[2 * i + 1];
            w[i] = bw.u;
        }
        #pragma unroll
        for (int slot = 0; slot < 2; ++slot) {
            unsigned int w0 = w[4 * slot], w1 = w[4 * slot + 1], w2 = w[4 * slot + 2], w3 = w[4 * slot + 3];
            unsigned int s0 = (unsigned int)__shfl_xor((int)w0, 32, 64);
            unsigned int s1 = (unsigned int)__shfl_xor((int)w1, 32, 64);
            unsigned int s2 = (unsigned int)__shfl_xor((int)w2, 32, 64);
            unsigned int s3 = (unsigned int)__shfl_xor((int)w3, 32, 64);
            union { unsigned int u[4]; bf16x8 v; } pa;
            pa.u[0] = hi ? s2 : w0;
            pa.u[1] = hi ? s3 : w1;
            pa.u[2] = hi ? w2 : s0;
            pa.u[3] = hi ? w3 : s1;
            #pragma unroll
            for (int dvb = 0; dvb < 2; ++dvb) {
                bf16x8 vf = *(const bf16x8*)&Vh[(size_t)(dvb * 32 + l31) * SEQ + k0 + slot * 16 + hi * 8];
                if (dvb == 0) o0 = __builtin_amdgcn_mfma_f32_32x32x16_bf16(pa.v, vf, o0, 0, 0, 0);
                else          o1 = __builtin_amdgcn_mfma_f32_32x32x16_bf16(pa.v, vf, o1, 0, 0, 0);
            }
        }
    }

    // ---- cross-wave O reduce, write out_heads ----
    #pragma unroll
    for (int r = 0; r < 16; ++r) {
        int q = (r & 3) + 8 * (r >> 2) + 4 * hi;
        ored[wv][q][l31]      = o0[r];
        ored[wv][q][32 + l31] = o1[r];
    }
    __syncthreads();
    {
        int q = tid >> 4, d0 = (tid & 15) * 4;
        float s[4] = {0.f, 0.f, 0.f, 0.f};
        #pragma unroll
        for (int w = 0; w < 8; ++w)
            #pragma unroll
            for (int j = 0; j < 4; ++j) s[j] += ored[w][q][d0 + j];
        int b = bh >> 4, h = bh & 15;
        bf16x4 ov = {(__bf16)s[0], (__bf16)s[1], (__bf16)s[2], (__bf16)s[3]};
        *(bf16x4*)&out_heads[((size_t)(b * SEQ + qbase + q)) * DMODEL + h * DK + d0] = ov;
    }
}

// ---------------------------------------------------------------------------
extern "C" void kernel_launch(void* const* d_in, const int* in_sizes, int n_in,
                              void* d_out, int out_size, void* d_ws, size_t ws_size,
                              hipStream_t stream) {
    const float* query = (const float*)d_in[0];
    const float* key   = (const float*)d_in[1];
    const float* value = (const float*)d_in[2];
    const float* w_q   = (const float*)d_in[3];
    const float* w_k   = (const float*)d_in[4];
    const float* w_v   = (const float*)d_in[5];
    const float* w_o   = (const float*)d_in[6];
    const float* lng   = (const float*)d_in[7];
    const float* lnb   = (const float*)d_in[8];

    char* ws = (char*)d_ws;
    __bf16* qn  = (__bf16*)(ws);                    // 8 MB  LN(query) bf16
    __bf16* kb  = (__bf16*)(ws + ( 8u << 20));      // 8 MB  key bf16
    __bf16* vb  = (__bf16*)(ws + (16u << 20));      // 8 MB  value bf16
    __bf16* wqb = (__bf16*)(ws + (24u << 20));      // 2 MB
    __bf16* wkb = (__bf16*)(ws + (26u << 20));      // 2 MB
    __bf16* wvb = (__bf16*)(ws + (28u << 20));      // 2 MB
    __bf16* wob = (__bf16*)(ws + (30u << 20));      // 2 MB
    __bf16* Qp  = (__bf16*)(ws + (32u << 20));      // 8 MB  [b,h,s,64] (x1/8)
    __bf16* Kp  = (__bf16*)(ws + (40u << 20));      // 8 MB  [b,h,s,64]
    __bf16* Vt  = (__bf16*)(ws + (48u << 20));      // 8 MB  [b,h,64,s']
    __bf16* oh  = (__bf16*)(ws + (56u << 20));      // 8 MB  attention out [4096,1024]

    float* out  = (float*)d_out;
    float* attn = out + (size_t)MROWS * DMODEL;

    ln_kernel<<<MROWS, 256, 0, stream>>>(query, lng, lnb, qn);
    cast_all<<<12288, 256, 0, stream>>>(key, value, w_q, w_k, w_v, w_o,
                                        kb, vb, wqb, wkb, wvb, wob);

    qkv_proj<<<768, 256, 0, stream>>>(qn, kb, vb, wqb, wkb, wvb, Qp, Kp, Vt);

    attn_kernel<<<2048, 512, 0, stream>>>(Qp, Kp, Vt, attn, oh);

    out_gemm<<<256, 256, 0, stream>>>(oh, wob, query, out);
}